// Round 5
// baseline (1226.570 us; speedup 1.0000x reference)
//
#include <hip/hip_runtime.h>
#include <hip/hip_bf16.h>
#include <math.h>
#include <stdint.h>

// HolomorphicEqProp: B=4096, D_IN=H=1024, D_OUT=256, steps=30.
// Round-14: latency-bound fix with BOTH levers (R12 lesson: TLP without
// ring depth regresses; R11/R13: 2 waves/SIMD cannot hide ds+L2 latency).
//  - 1024 threads = 16 waves = 4/SIMD, still 1 block/CU (LDS 132KB).
//  - Sweep moved to mfma_f32_32x32x16_bf16: wave tile 32Mx32N, ONE h
//    stream (B-frag lane=batch-row, 16B contiguous), ring-8 = 32 VGPR ->
//    deep prefetch lead (~1000 cyc) AND 4 waves/SIMD fit in 128 VGPR.
//  - Per K-step: 1 ds_read_b128 + 1 global load + 1 MFMA (half the MFMA
//    instr count of 16x16 for same FLOP; same LDS bytes).
//  - b_rec folded into MFMA C-init (acc=brec); b_in folded into xpr.
//  - C/D layout (m74/m101-verified): col=lane&31,
//    row=(reg&3)+8*(reg>>2)+4*(lane>>5) -> 4x 8B packed stores per lane.
//  - Barrier: R11 lockstep XCD-L2-resident form (R13's distributed gates
//    were neutral-to-worse; reverted).

#define EPSF 1e-12f

typedef short bf16x8 __attribute__((ext_vector_type(8)));
typedef float f32x4 __attribute__((ext_vector_type(4)));
typedef float f32x16 __attribute__((ext_vector_type(16)));

struct Mods { float m[32]; };

__device__ __forceinline__ unsigned short f2bf(float f) {
  union { float f; unsigned u; } v; v.f = f;
  unsigned r = v.u + 0x7FFFu + ((v.u >> 16) & 1u);  // RNE
  return (unsigned short)(r >> 16);
}

// packed f32x2 -> bf16x2 (RNE), single VALU op
__device__ __forceinline__ unsigned cvt_pk_bf16(float lo, float hi) {
  unsigned r;
  asm("v_cvt_pk_bf16_f32 %0, %1, %2" : "=v"(r) : "v"(lo), "v"(hi));
  return r;
}

// tanh(x) = 1 - 2/(exp(2x)+1). Saturates exactly; abs err ~1e-7 << bf16 eps.
__device__ __forceinline__ float tanh_fast(float x) {
  float e = __expf(2.0f * x);
  float r = __builtin_amdgcn_rcpf(e + 1.0f);
  return fmaf(-2.0f, r, 1.0f);
}

// async global->LDS (only in gemm_bt0: R1-validated pattern)
__device__ __forceinline__ void async16(const void* g, void* l) {
  __builtin_amdgcn_global_load_lds(
      (__attribute__((address_space(1))) void*)(uintptr_t)(g),
      (__attribute__((address_space(3))) void*)(unsigned)(uintptr_t)(l),
      16, 0, 0);
}

__device__ __forceinline__ float block_reduce_sum(float x) {
#pragma unroll
  for (int o = 32; o > 0; o >>= 1) x += __shfl_down(x, o, 64);
  __shared__ float sm[8];
  int lane = threadIdx.x & 63, w = threadIdx.x >> 6;
  if (lane == 0) sm[w] = x;
  __syncthreads();
  float t = 0.f;
  if (threadIdx.x == 0) {
    int nw = (int)(blockDim.x >> 6);
    for (int i = 0; i < nw; ++i) t += sm[i];
  }
  return t;
}

// ---------------- fused spectral-norm setup (fp32, exact) ----------------

__global__ void spec_col3(const float* __restrict__ Wi, const float* __restrict__ Wr,
                          const float* __restrict__ Wo, const float* __restrict__ ui,
                          const float* __restrict__ ur, const float* __restrict__ uo,
                          float* __restrict__ v) {
  int z = blockIdx.z;
  const float* W = (z == 0) ? Wi : (z == 1) ? Wr : Wo;
  const float* u = (z == 0) ? ui : (z == 1) ? ur : uo;
  int M = (z == 2) ? 256 : 1024;
  int i0 = blockIdx.y * 64;
  if (i0 >= M) return;
  int j = blockIdx.x * blockDim.x + threadIdx.x;
  float acc = 0.f;
  for (int i = i0; i < i0 + 64; ++i)
    acc += W[(size_t)i * 1024 + j] * u[i];
  atomicAdd(&v[z * 1024 + j], acc);
}

__global__ void norm3(const float* __restrict__ v, float* __restrict__ S) {
  int z = blockIdx.x;
  float acc = 0.f;
  for (int i = threadIdx.x; i < 1024; i += blockDim.x) {
    float x = v[z * 1024 + i];
    acc += x * x;
  }
  float t = block_reduce_sum(acc);
  if (threadIdx.x == 0) S[z] = t;
}

__global__ void rowsq3(const float* __restrict__ Wi, const float* __restrict__ Wr,
                       const float* __restrict__ Wo, const float* __restrict__ v,
                       float* __restrict__ S) {
  int bid = blockIdx.x;
  int z = (bid < 1024) ? 0 : (bid < 2048) ? 1 : 2;
  int row = bid - ((z == 0) ? 0 : (z == 1) ? 1024 : 2048);
  const float* W = (z == 0) ? Wi : (z == 1) ? Wr : Wo;
  const float* vv = v + z * 1024;
  float acc = 0.f;
  for (int j = threadIdx.x; j < 1024; j += blockDim.x)
    acc += W[(size_t)row * 1024 + j] * vv[j];
  float r = block_reduce_sum(acc);
  if (threadIdx.x == 0) atomicAdd(&S[3 + z], r * r);
}

__global__ void spec_finalize(float* S) {
  int m = threadIdx.x;
  if (m < 3) {
    float nv = sqrtf(S[m]);
    float inv = 1.f / (nv + EPSF);
    float u2sq = S[3 + m] * inv * inv;
    float nu = sqrtf(u2sq);
    float sigma = u2sq / (nu + EPSF);
    S[6 + m] = 1.f / sigma;
  }
}

__device__ __forceinline__ ushort4 cvt4e(float4 w, float s) {
  ushort4 r;
  r.x = f2bf(w.x * s); r.y = f2bf(w.y * s); r.z = f2bf(w.z * s); r.w = f2bf(w.w * s);
  return r;
}

__global__ void cvt_all(const float4* __restrict__ Wi, const float4* __restrict__ Wr,
                        const float4* __restrict__ Wo, const float4* __restrict__ x,
                        const float* __restrict__ S,
                        ushort4* __restrict__ oWi, ushort4* __restrict__ oWr,
                        ushort4* __restrict__ oWo, ushort4* __restrict__ ox) {
  float s6 = S[6], s7 = S[7], s8 = S[8];
  int stride = gridDim.x * blockDim.x;
  int t0 = blockIdx.x * blockDim.x + threadIdx.x;
  for (int i = t0; i < 262144; i += stride) oWi[i] = cvt4e(Wi[i], s6);
  for (int i = t0; i < 262144; i += stride) oWr[i] = cvt4e(Wr[i], s7);
  for (int i = t0; i < 65536; i += stride) oWo[i] = cvt4e(Wo[i], s8);
  for (int i = t0; i < 1048576; i += stride) ox[i] = cvt4e(x[i], 1.0f);
}

// C = A[M,K] . B[N,K]^T + bias[n], fp32 out. 64x128 tile (validated R5/R7).
__global__ __launch_bounds__(256) void gemm_bt0(
    const unsigned short* __restrict__ A, const unsigned short* __restrict__ B,
    const float* __restrict__ bias, float* __restrict__ outF,
    int M, int N, int K) {
  constexpr int BM = 64, BN = 128, BK = 32;
  __shared__ __align__(16) unsigned short As[BM * BK];
  __shared__ __align__(16) unsigned short Bs[BN * BK];
  const int tid = threadIdx.x;
  const int wave = tid >> 6, lane = tid & 63;
  const int m0 = blockIdx.x * BM, n0 = blockIdx.y * BN;
  const int wm = (wave >> 1) * 32, wn = (wave & 1) * 64;
  const int lrow = lane & 15, quad = lane >> 4;

  f32x4 acc[2][4] = {};

  for (int k0 = 0; k0 < K; k0 += BK) {
    {
      int e = tid * 8;
      int r = e >> 5, c = e & 31;
      async16(&A[(size_t)(m0 + r) * K + k0 + c], &As[e]);
#pragma unroll
      for (int inst = 0; inst < 2; ++inst) {
        int eb = inst * 2048 + tid * 8;
        int rb = eb >> 5, cb = eb & 31;
        async16(&B[(size_t)(n0 + rb) * K + k0 + cb], &Bs[eb]);
      }
    }
    __syncthreads();

    bf16x8 af[2], bfr[4];
#pragma unroll
    for (int i = 0; i < 2; ++i)
      af[i] = *(const bf16x8*)&As[(wm + i * 16 + lrow) * BK + quad * 8];
#pragma unroll
    for (int j = 0; j < 4; ++j)
      bfr[j] = *(const bf16x8*)&Bs[(wn + j * 16 + lrow) * BK + quad * 8];
#pragma unroll
    for (int i = 0; i < 2; ++i)
#pragma unroll
      for (int j = 0; j < 4; ++j)
        acc[i][j] = __builtin_amdgcn_mfma_f32_16x16x32_bf16(af[i], bfr[j], acc[i][j], 0, 0, 0);
    __syncthreads();
  }

#pragma unroll
  for (int i = 0; i < 2; ++i)
#pragma unroll
    for (int j = 0; j < 4; ++j) {
      int col = n0 + wn + j * 16 + lrow;
      float bv = bias[col];
#pragma unroll
      for (int r = 0; r < 4; ++r) {
        int row = m0 + wm + i * 16 + quad * 4 + r;
        outF[(size_t)row * N + col] = acc[i][j][r] + bv;
      }
    }
}

// ---------------- cooperative RNN ----------------

// 1024 threads: each copies 64 shorts of the 64x1024 slice into padded ws.
__device__ __forceinline__ void load_ws(const unsigned short* __restrict__ src,
                                        unsigned short* ws, int tid) {
  int r = tid & 63, s = tid >> 6;  // s in 0..15
  const unsigned short* p = src + (size_t)r * 1024 + s * 64;
  unsigned short* d = ws + r * 1032 + s * 64;
#pragma unroll
  for (int j = 0; j < 8; ++j)
    *(bf16x8*)(d + j * 8) = *(const bf16x8*)(p + j * 8);
}

// 32x32x16 K-sweep: 64 K-steps, single h stream, ring-8.
// a (A-op, Wr/Wi from LDS): lane reads W[nrow = nb + (lane&31)][kc*16 + hi*8],
// b (B-op, h from global):  lane reads h[m0 + (lane&31)][kc*16 + hi*8].
// wsa/gb are per-lane base pointers (include row*stride + hi*8).
__device__ __forceinline__ void ksweep32(const unsigned short* __restrict__ gb,
                                         const unsigned short* wsa, f32x16& acc) {
  bf16x8 pb[8];
#pragma unroll
  for (int i = 0; i < 8; ++i) pb[i] = *(const bf16x8*)(gb + i * 16);
#pragma unroll 1
  for (int kb = 0; kb < 64; kb += 8) {
#define PHASE(P)                                                                 \
    {                                                                            \
      const int kc = kb + P;                                                     \
      bf16x8 b = pb[P];                                                          \
      const int kn = (kc + 8) & 63;                                              \
      pb[P] = *(const bf16x8*)(gb + kn * 16);                                    \
      bf16x8 a = *(const bf16x8*)(wsa + kc * 16);                                \
      __builtin_amdgcn_s_setprio(1);                                             \
      acc = __builtin_amdgcn_mfma_f32_32x32x16_bf16(a, b, acc, 0, 0, 0);         \
      __builtin_amdgcn_s_setprio(0);                                             \
    }
    PHASE(0) PHASE(1) PHASE(2) PHASE(3) PHASE(4) PHASE(5) PHASE(6) PHASE(7)
#undef PHASE
  }
}

// ---- slow/fallback barrier (agent scope, R9-validated form) ----
__device__ __forceinline__ void group_barrier(unsigned* ctr, unsigned target) {
  __syncthreads();  // all waves' stores issued & drained to L2
  if (threadIdx.x == 0) {
    __hip_atomic_fetch_add(ctr, 1u, __ATOMIC_RELEASE, __HIP_MEMORY_SCOPE_AGENT);
    while (__hip_atomic_load(ctr, __ATOMIC_RELAXED, __HIP_MEMORY_SCOPE_AGENT) < target)
      __builtin_amdgcn_s_sleep(2);
    (void)__hip_atomic_load(ctr, __ATOMIC_ACQUIRE, __HIP_MEMORY_SCOPE_AGENT);
  }
  __syncthreads();
}

// ---- fast barrier (group verified XCD-homogeneous): h stays in XCD L2 ----
// (R10-validated: WRITE_SIZE 246 MB -> 22 MB.) Relaxed MALL signal/poll, one
// L1-only invalidate (buffer_inv sc0) on the consumer.
__device__ __forceinline__ void group_barrier_l2(unsigned* ctr, unsigned target) {
  __syncthreads();  // h stores of all 16 waves now visible in XCD L2
  if (threadIdx.x == 0) {
    __hip_atomic_fetch_add(ctr, 1u, __ATOMIC_RELAXED, __HIP_MEMORY_SCOPE_AGENT);
    while (__hip_atomic_load(ctr, __ATOMIC_RELAXED, __HIP_MEMORY_SCOPE_AGENT) < target)
      __builtin_amdgcn_s_sleep(2);
    asm volatile("buffer_inv sc0" ::: "memory");  // invalidate this CU's L1 only
  }
  __syncthreads();
}

// 256 blocks x 1024 threads, 1 block/CU, 16 waves = 4/SIMD. Block (mt,nt):
// M rows [mt*256,+256), N cols [nt*64,+64). Wave w: m-pos w&7 (32 rows),
// n-pos w>>3 (32 cols). Group = blocks sharing mt (bid&15), closed under
// the h dependency, swizzled onto one XCD.
// bar slots (128 B/group): [0]=step ctr, [1]=publish, [2]=XCD mask.
__global__ __launch_bounds__(1024, 1) void rnn_coop(
    const unsigned short* __restrict__ x_bf,  // [4096][1024] bf16
    const unsigned short* __restrict__ Wi,    // [1024][1024] bf16 (scaled)
    const unsigned short* __restrict__ Wr,    // [1024][1024] bf16 (scaled)
    const float* __restrict__ b_in,
    const float* __restrict__ b_rec,
    unsigned short* __restrict__ hA,
    unsigned short* __restrict__ hB,
    unsigned* __restrict__ bar,
    Mods mods) {
  __shared__ __align__(16) unsigned short ws[64 * 1032];
  __shared__ unsigned fastflag;

  const int tid = threadIdx.x;
  const int w = tid >> 6, lane = tid & 63;
  const int lm = lane & 31;       // m-col in D; batch row for B-frag
  const int hi = lane >> 5;       // k-half
  const int bid = (int)blockIdx.x;
  const int mt = (bid & 7) * 2 + ((bid >> 3) & 1);
  const int nt = bid >> 4;
  const int gid = bid & 15;
  const int m0 = mt * 256 + (w & 7) * 32;
  const int nb = (w >> 3) * 32;   // wave's col offset inside the 64-col block
  const int n0 = nt * 64;
  unsigned* ctr = bar + gid * 32;  // 128 B per group

  // ---- publish this block's physical XCD at entry (R10 protocol) ----
  if (tid == 0) {
    unsigned xcc;
    asm volatile("s_getreg_b32 %0, hwreg(HW_REG_XCC_ID)" : "=s"(xcc));
    __hip_atomic_fetch_or(ctr + 2, 1u << (xcc & 15u), __ATOMIC_RELAXED,
                          __HIP_MEMORY_SCOPE_AGENT);
    __hip_atomic_fetch_add(ctr + 1, 1u, __ATOMIC_RELEASE, __HIP_MEMORY_SCOPE_AGENT);
  }

  // D-layout: reg r -> n = n0 + nb + 4*hi + 8*(r>>2) + (r&3), m = m0 + lm.
  const int nn0 = n0 + nb + 4 * hi;
  f32x16 brecf;
  {
#pragma unroll
    for (int q = 0; q < 4; ++q) {
      float4 t4 = *(const float4*)&b_rec[nn0 + 8 * q];
      brecf[4 * q + 0] = t4.x; brecf[4 * q + 1] = t4.y;
      brecf[4 * q + 2] = t4.z; brecf[4 * q + 3] = t4.w;
    }
  }

  // per-lane LDS base: row nb+lm, k-half hi
  const unsigned short* wsa = ws + (nb + lm) * 1032 + hi * 8;

  // ---- phase A: xproj slice (registers) via Wi slice in ws ----
  load_ws(Wi + (size_t)n0 * 1024, ws, tid);
  __syncthreads();
  f32x16 xpr;
  {
#pragma unroll
    for (int q = 0; q < 4; ++q) {  // init with b_in (folded permanently)
      float4 t4 = *(const float4*)&b_in[nn0 + 8 * q];
      xpr[4 * q + 0] = t4.x; xpr[4 * q + 1] = t4.y;
      xpr[4 * q + 2] = t4.z; xpr[4 * q + 3] = t4.w;
    }
    ksweep32(&x_bf[(size_t)(m0 + lm) * 1024 + hi * 8], wsa, xpr);
  }
  __syncthreads();  // all ws (Wi) reads done

  // ---- Wr slice -> ws (resident for all steps) ----
  load_ws(Wr + (size_t)n0 * 1024, ws, tid);

  // ---- resolve group homogeneity (relaxed MALL reads only; no acquire) ----
  if (tid == 0) {
    while (__hip_atomic_load(ctr + 1, __ATOMIC_RELAXED, __HIP_MEMORY_SCOPE_AGENT) < 16u)
      __builtin_amdgcn_s_sleep(2);
    asm volatile("" ::: "memory");  // keep mask read after the spin
    unsigned m = __hip_atomic_load(ctr + 2, __ATOMIC_RELAXED, __HIP_MEMORY_SCOPE_AGENT);
    fastflag = ((m & (m - 1u)) == 0u) ? 1u : 0u;
  }

  // ---- t=0: h = tanh(xpr + brec) (mod(0)=1, h_prev=0) ----
  unsigned short* cur = hA;
  unsigned short* nxt = hB;
  {
    unsigned short* hrow = &cur[(size_t)(m0 + lm) * 1024 + nn0];
#pragma unroll
    for (int q = 0; q < 4; ++q) {
      float h0 = tanh_fast(xpr[4 * q + 0] + brecf[4 * q + 0]);
      float h1 = tanh_fast(xpr[4 * q + 1] + brecf[4 * q + 1]);
      float h2 = tanh_fast(xpr[4 * q + 2] + brecf[4 * q + 2]);
      float h3 = tanh_fast(xpr[4 * q + 3] + brecf[4 * q + 3]);
      uint2 pk = {cvt_pk_bf16(h0, h1), cvt_pk_bf16(h2, h3)};
      *(uint2*)(hrow + 8 * q) = pk;
    }
  }
  __syncthreads();  // ws (Wr) ready + fastflag published
  const bool fastp = (fastflag != 0u);

  // ---- steps t = 1..29 ----
#pragma unroll 1
  for (int t = 1; t < 30; ++t) {
    if (fastp) group_barrier_l2(ctr, 16u * (unsigned)t);  // h(t-1) via XCD L2
    else       group_barrier(ctr, 16u * (unsigned)t);     // device-scope fallback
    const float mod = mods.m[t];
    f32x16 acc = brecf;  // fold b_rec into C-init
    ksweep32(&cur[(size_t)(m0 + lm) * 1024 + hi * 8], wsa, acc);
    unsigned short* hrow = &nxt[(size_t)(m0 + lm) * 1024 + nn0];
#pragma unroll
    for (int q = 0; q < 4; ++q) {
      float h0 = tanh_fast(fmaf(acc[4 * q + 0], mod, xpr[4 * q + 0]));
      float h1 = tanh_fast(fmaf(acc[4 * q + 1], mod, xpr[4 * q + 1]));
      float h2 = tanh_fast(fmaf(acc[4 * q + 2], mod, xpr[4 * q + 2]));
      float h3 = tanh_fast(fmaf(acc[4 * q + 3], mod, xpr[4 * q + 3]));
      uint2 pk = {cvt_pk_bf16(h0, h1), cvt_pk_bf16(h2, h3)};
      *(uint2*)(hrow + 8 * q) = pk;
    }
    unsigned short* tmp = cur; cur = nxt; nxt = tmp;
  }
  // h29 ends in hB (odd number of steps after t=0); kernel-end dispatch
  // release fence writes back dirty L2 for gemm_bt0.
}

extern "C" void kernel_launch(void* const* d_in, const int* in_sizes, int n_in,
                              void* d_out, int out_size, void* d_ws, size_t ws_size,
                              hipStream_t stream) {
  const float* x     = (const float*)d_in[0];
  const float* W_in  = (const float*)d_in[1];
  const float* b_in  = (const float*)d_in[2];
  const float* W_rec = (const float*)d_in[3];
  const float* b_rec = (const float*)d_in[4];
  const float* W_out = (const float*)d_in[5];
  const float* b_out = (const float*)d_in[6];
  const float* u_in  = (const float*)d_in[7];
  const float* u_rec = (const float*)d_in[8];
  const float* u_out = (const float*)d_in[9];

  const int B = 4096, H = 1024, DOUT = 256;

  char* w = (char*)d_ws;
  float* S = (float*)w;                          // 256 floats
  float* v = S + 256;                            // 3 x 1024 floats
  unsigned* bar = (unsigned*)(w + 14336);        // 16 groups x 128 B
  unsigned short* Wi_bf = (unsigned short*)(w + (1 << 14));
  unsigned short* Wr_bf = Wi_bf + (size_t)H * H;
  unsigned short* Wo_bf = Wr_bf + (size_t)H * H;
  unsigned short* x_bf  = Wo_bf + (size_t)DOUT * H;
  unsigned short* hA = x_bf + (size_t)B * H;
  unsigned short* hB = hA + (size_t)B * H;

  hipMemsetAsync(w, 0, 1 << 14, stream);  // zero S, v, barrier counters+masks

  dim3 t256(256);
  spec_col3<<<dim3(4, 16, 3), t256, 0, stream>>>(W_in, W_rec, W_out, u_in, u_rec, u_out, v);
  norm3<<<3, t256, 0, stream>>>(v, S);
  rowsq3<<<2304, t256, 0, stream>>>(W_in, W_rec, W_out, v, S);
  spec_finalize<<<1, 64, 0, stream>>>(S);
  cvt_all<<<1024, t256, 0, stream>>>((const float4*)W_in, (const float4*)W_rec,
                                     (const float4*)W_out, (const float4*)x, S,
                                     (ushort4*)Wi_bf, (ushort4*)Wr_bf,
                                     (ushort4*)Wo_bf, (ushort4*)x_bf);

  Mods mods;
  for (int t = 0; t < 32; ++t) mods.m[t] = (float)(1.0 + 0.1 * sin(0.3 * (double)t));
  {
    void* args[] = {(void*)&x_bf, (void*)&Wi_bf, (void*)&Wr_bf, (void*)&b_in,
                    (void*)&b_rec, (void*)&hA, (void*)&hB, (void*)&bar, (void*)&mods};
    hipLaunchCooperativeKernel((const void*)rnn_coop, dim3(256), dim3(1024),
                               args, 0, stream);
  }

  // out = h29 @ Wo_n^T + b_out
  gemm_bt0<<<dim3(B / 64, DOUT / 128), t256, 0, stream>>>(
      hB, Wo_bf, b_out, (float*)d_out, B, DOUT, H);
}

// Round 6
// 781.001 us; speedup vs baseline: 1.5705x; 1.5705x over previous
//
#include <hip/hip_runtime.h>
#include <hip/hip_bf16.h>
#include <math.h>
#include <stdint.h>

// HolomorphicEqProp: B=4096, D_IN=H=1024, D_OUT=256, steps=30.
// Round-15: back to the R11 structure (665 us; best known), plus LDS-frag
// register double-buffering. R14's counter pair (bank-conflict 0, MfmaUtil
// 9.5%) killed the bank-conflict theory and confirmed: ds_read latency is
// exposed INSIDE each phase (reads issued and waited in the same phase).
// Fix: process K-phases in PAIRS (8 ds_reads -> 16 MFMAs) with the pair's
// Wr frags prefetched ONE PAIR AHEAD into alternating named buffers
// bqA/bqB (compile-time indices only; rule-#20 safe). Compiler emits a
// counted lgkmcnt wait -> current frags have a full pair of MFMA work in
// flight before use. +64 VGPR (96->~160): free at 1 block/CU (LDS cap).
// Proven parts kept EXACTLY: 512 thr, 16x16x32 swapped-operand MFMA,
// ring-8 global h prefetch, cvt_pk epilogue, tanh_fast, R10 XCD-L2
// lockstep barrier + agent fallback, setprio around MFMA clusters.

#define EPSF 1e-12f

typedef short bf16x8 __attribute__((ext_vector_type(8)));
typedef float f32x4 __attribute__((ext_vector_type(4)));

struct Mods { float m[32]; };

__device__ __forceinline__ unsigned short f2bf(float f) {
  union { float f; unsigned u; } v; v.f = f;
  unsigned r = v.u + 0x7FFFu + ((v.u >> 16) & 1u);  // RNE
  return (unsigned short)(r >> 16);
}

// packed f32x2 -> bf16x2 (RNE), single VALU op
__device__ __forceinline__ unsigned cvt_pk_bf16(float lo, float hi) {
  unsigned r;
  asm("v_cvt_pk_bf16_f32 %0, %1, %2" : "=v"(r) : "v"(lo), "v"(hi));
  return r;
}

// tanh(x) = 1 - 2/(exp(2x)+1). Saturates exactly; abs err ~1e-7 << bf16 eps.
__device__ __forceinline__ float tanh_fast(float x) {
  float e = __expf(2.0f * x);
  float r = __builtin_amdgcn_rcpf(e + 1.0f);
  return fmaf(-2.0f, r, 1.0f);
}

// async global->LDS (only in gemm_bt0: R1-validated pattern)
__device__ __forceinline__ void async16(const void* g, void* l) {
  __builtin_amdgcn_global_load_lds(
      (__attribute__((address_space(1))) void*)(uintptr_t)(g),
      (__attribute__((address_space(3))) void*)(unsigned)(uintptr_t)(l),
      16, 0, 0);
}

__device__ __forceinline__ float block_reduce_sum(float x) {
#pragma unroll
  for (int o = 32; o > 0; o >>= 1) x += __shfl_down(x, o, 64);
  __shared__ float sm[8];
  int lane = threadIdx.x & 63, w = threadIdx.x >> 6;
  if (lane == 0) sm[w] = x;
  __syncthreads();
  float t = 0.f;
  if (threadIdx.x == 0) {
    int nw = (int)(blockDim.x >> 6);
    for (int i = 0; i < nw; ++i) t += sm[i];
  }
  return t;
}

// ---------------- fused spectral-norm setup (fp32, exact) ----------------

__global__ void spec_col3(const float* __restrict__ Wi, const float* __restrict__ Wr,
                          const float* __restrict__ Wo, const float* __restrict__ ui,
                          const float* __restrict__ ur, const float* __restrict__ uo,
                          float* __restrict__ v) {
  int z = blockIdx.z;
  const float* W = (z == 0) ? Wi : (z == 1) ? Wr : Wo;
  const float* u = (z == 0) ? ui : (z == 1) ? ur : uo;
  int M = (z == 2) ? 256 : 1024;
  int i0 = blockIdx.y * 64;
  if (i0 >= M) return;
  int j = blockIdx.x * blockDim.x + threadIdx.x;
  float acc = 0.f;
  for (int i = i0; i < i0 + 64; ++i)
    acc += W[(size_t)i * 1024 + j] * u[i];
  atomicAdd(&v[z * 1024 + j], acc);
}

__global__ void norm3(const float* __restrict__ v, float* __restrict__ S) {
  int z = blockIdx.x;
  float acc = 0.f;
  for (int i = threadIdx.x; i < 1024; i += blockDim.x) {
    float x = v[z * 1024 + i];
    acc += x * x;
  }
  float t = block_reduce_sum(acc);
  if (threadIdx.x == 0) S[z] = t;
}

__global__ void rowsq3(const float* __restrict__ Wi, const float* __restrict__ Wr,
                       const float* __restrict__ Wo, const float* __restrict__ v,
                       float* __restrict__ S) {
  int bid = blockIdx.x;
  int z = (bid < 1024) ? 0 : (bid < 2048) ? 1 : 2;
  int row = bid - ((z == 0) ? 0 : (z == 1) ? 1024 : 2048);
  const float* W = (z == 0) ? Wi : (z == 1) ? Wr : Wo;
  const float* vv = v + z * 1024;
  float acc = 0.f;
  for (int j = threadIdx.x; j < 1024; j += blockDim.x)
    acc += W[(size_t)row * 1024 + j] * vv[j];
  float r = block_reduce_sum(acc);
  if (threadIdx.x == 0) atomicAdd(&S[3 + z], r * r);
}

__global__ void spec_finalize(float* S) {
  int m = threadIdx.x;
  if (m < 3) {
    float nv = sqrtf(S[m]);
    float inv = 1.f / (nv + EPSF);
    float u2sq = S[3 + m] * inv * inv;
    float nu = sqrtf(u2sq);
    float sigma = u2sq / (nu + EPSF);
    S[6 + m] = 1.f / sigma;
  }
}

__device__ __forceinline__ ushort4 cvt4e(float4 w, float s) {
  ushort4 r;
  r.x = f2bf(w.x * s); r.y = f2bf(w.y * s); r.z = f2bf(w.z * s); r.w = f2bf(w.w * s);
  return r;
}

__global__ void cvt_all(const float4* __restrict__ Wi, const float4* __restrict__ Wr,
                        const float4* __restrict__ Wo, const float4* __restrict__ x,
                        const float* __restrict__ S,
                        ushort4* __restrict__ oWi, ushort4* __restrict__ oWr,
                        ushort4* __restrict__ oWo, ushort4* __restrict__ ox) {
  float s6 = S[6], s7 = S[7], s8 = S[8];
  int stride = gridDim.x * blockDim.x;
  int t0 = blockIdx.x * blockDim.x + threadIdx.x;
  for (int i = t0; i < 262144; i += stride) oWi[i] = cvt4e(Wi[i], s6);
  for (int i = t0; i < 262144; i += stride) oWr[i] = cvt4e(Wr[i], s7);
  for (int i = t0; i < 65536; i += stride) oWo[i] = cvt4e(Wo[i], s8);
  for (int i = t0; i < 1048576; i += stride) ox[i] = cvt4e(x[i], 1.0f);
}

// C = A[M,K] . B[N,K]^T + bias[n], fp32 out. 64x128 tile (validated R5/R7).
__global__ __launch_bounds__(256) void gemm_bt0(
    const unsigned short* __restrict__ A, const unsigned short* __restrict__ B,
    const float* __restrict__ bias, float* __restrict__ outF,
    int M, int N, int K) {
  constexpr int BM = 64, BN = 128, BK = 32;
  __shared__ __align__(16) unsigned short As[BM * BK];
  __shared__ __align__(16) unsigned short Bs[BN * BK];
  const int tid = threadIdx.x;
  const int wave = tid >> 6, lane = tid & 63;
  const int m0 = blockIdx.x * BM, n0 = blockIdx.y * BN;
  const int wm = (wave >> 1) * 32, wn = (wave & 1) * 64;
  const int lrow = lane & 15, quad = lane >> 4;

  f32x4 acc[2][4] = {};

  for (int k0 = 0; k0 < K; k0 += BK) {
    {
      int e = tid * 8;
      int r = e >> 5, c = e & 31;
      async16(&A[(size_t)(m0 + r) * K + k0 + c], &As[e]);
#pragma unroll
      for (int inst = 0; inst < 2; ++inst) {
        int eb = inst * 2048 + tid * 8;
        int rb = eb >> 5, cb = eb & 31;
        async16(&B[(size_t)(n0 + rb) * K + k0 + cb], &Bs[eb]);
      }
    }
    __syncthreads();

    bf16x8 af[2], bfr[4];
#pragma unroll
    for (int i = 0; i < 2; ++i)
      af[i] = *(const bf16x8*)&As[(wm + i * 16 + lrow) * BK + quad * 8];
#pragma unroll
    for (int j = 0; j < 4; ++j)
      bfr[j] = *(const bf16x8*)&Bs[(wn + j * 16 + lrow) * BK + quad * 8];
#pragma unroll
    for (int i = 0; i < 2; ++i)
#pragma unroll
      for (int j = 0; j < 4; ++j)
        acc[i][j] = __builtin_amdgcn_mfma_f32_16x16x32_bf16(af[i], bfr[j], acc[i][j], 0, 0, 0);
    __syncthreads();
  }

#pragma unroll
  for (int i = 0; i < 2; ++i)
#pragma unroll
    for (int j = 0; j < 4; ++j) {
      int col = n0 + wn + j * 16 + lrow;
      float bv = bias[col];
#pragma unroll
      for (int r = 0; r < 4; ++r) {
        int row = m0 + wm + i * 16 + quad * 4 + r;
        outF[(size_t)row * N + col] = acc[i][j][r] + bv;
      }
    }
}

// ---------------- cooperative RNN ----------------

// 512 threads: each copies 128 shorts of the 64x1024 slice into padded ws.
__device__ __forceinline__ void load_ws(const unsigned short* __restrict__ src,
                                        unsigned short* ws, int tid) {
  int r = tid & 63, s = tid >> 6;
  const unsigned short* p = src + (size_t)r * 1024 + s * 128;
  unsigned short* d = ws + r * 1032 + s * 128;
#pragma unroll
  for (int j = 0; j < 16; ++j)
    *(bf16x8*)(d + j * 8) = *(const bf16x8*)(p + j * 8);
}

// -------- K-sweep with LDS-frag double-buffer + global ring-8 --------
// Phases processed in PAIRS: 8 ds_reads (next pair, into the alternate
// named buffer) then 16 MFMAs (current pair). Counted lgkm wait => the
// frags used have been in flight for >= one full pair. All buffer and
// ring indices are compile-time (rule #20).

#define PFPAIR(DST, KP)                                                          \
  {                                                                              \
    const int kp_ = (KP) & 31;                                                   \
    _Pragma("unroll")                                                            \
    for (int nf = 0; nf < 4; ++nf) {                                             \
      DST[nf]     = *(const bf16x8*)&ws[(nf * 16 + lrow) * 1032 + kp_ * 32 + quad * 8];       \
      DST[nf + 4] = *(const bf16x8*)&ws[(nf * 16 + lrow) * 1032 + (kp_ + 1) * 32 + quad * 8]; \
    }                                                                            \
  }

#define MFMAPAIR(BUF, OFF)                                                       \
  {                                                                              \
    const int kc0 = kb + (OFF), kc1 = kc0 + 1;                                   \
    bf16x8 a00 = pa0[(OFF) & 7], a10 = pa1[(OFF) & 7];                           \
    bf16x8 a01 = pa0[((OFF) + 1) & 7], a11 = pa1[((OFF) + 1) & 7];               \
    pa0[(OFF) & 7] = *(const bf16x8*)(a0p + ((kc0 + 8) & 31) * 32);              \
    pa1[(OFF) & 7] = *(const bf16x8*)(a1p + ((kc0 + 8) & 31) * 32);              \
    pa0[((OFF) + 1) & 7] = *(const bf16x8*)(a0p + ((kc1 + 8) & 31) * 32);        \
    pa1[((OFF) + 1) & 7] = *(const bf16x8*)(a1p + ((kc1 + 8) & 31) * 32);        \
    __builtin_amdgcn_s_setprio(1);                                               \
    acc[0][0] = __builtin_amdgcn_mfma_f32_16x16x32_bf16(BUF[0], a00, acc[0][0], 0, 0, 0); \
    acc[1][0] = __builtin_amdgcn_mfma_f32_16x16x32_bf16(BUF[0], a10, acc[1][0], 0, 0, 0); \
    acc[0][1] = __builtin_amdgcn_mfma_f32_16x16x32_bf16(BUF[1], a00, acc[0][1], 0, 0, 0); \
    acc[1][1] = __builtin_amdgcn_mfma_f32_16x16x32_bf16(BUF[1], a10, acc[1][1], 0, 0, 0); \
    acc[0][2] = __builtin_amdgcn_mfma_f32_16x16x32_bf16(BUF[2], a00, acc[0][2], 0, 0, 0); \
    acc[1][2] = __builtin_amdgcn_mfma_f32_16x16x32_bf16(BUF[2], a10, acc[1][2], 0, 0, 0); \
    acc[0][3] = __builtin_amdgcn_mfma_f32_16x16x32_bf16(BUF[3], a00, acc[0][3], 0, 0, 0); \
    acc[1][3] = __builtin_amdgcn_mfma_f32_16x16x32_bf16(BUF[3], a10, acc[1][3], 0, 0, 0); \
    acc[0][0] = __builtin_amdgcn_mfma_f32_16x16x32_bf16(BUF[4], a01, acc[0][0], 0, 0, 0); \
    acc[1][0] = __builtin_amdgcn_mfma_f32_16x16x32_bf16(BUF[4], a11, acc[1][0], 0, 0, 0); \
    acc[0][1] = __builtin_amdgcn_mfma_f32_16x16x32_bf16(BUF[5], a01, acc[0][1], 0, 0, 0); \
    acc[1][1] = __builtin_amdgcn_mfma_f32_16x16x32_bf16(BUF[5], a11, acc[1][1], 0, 0, 0); \
    acc[0][2] = __builtin_amdgcn_mfma_f32_16x16x32_bf16(BUF[6], a01, acc[0][2], 0, 0, 0); \
    acc[1][2] = __builtin_amdgcn_mfma_f32_16x16x32_bf16(BUF[6], a11, acc[1][2], 0, 0, 0); \
    acc[0][3] = __builtin_amdgcn_mfma_f32_16x16x32_bf16(BUF[7], a01, acc[0][3], 0, 0, 0); \
    acc[1][3] = __builtin_amdgcn_mfma_f32_16x16x32_bf16(BUF[7], a11, acc[1][3], 0, 0, 0); \
    __builtin_amdgcn_s_setprio(0);                                               \
  }

__device__ __forceinline__ void ksweep(const unsigned short* __restrict__ a0p,
                                       const unsigned short* __restrict__ a1p,
                                       const unsigned short* ws, int lrow, int quad,
                                       f32x4 acc[2][4]) {
  bf16x8 pa0[8], pa1[8];
#pragma unroll
  for (int i = 0; i < 8; ++i) {
    pa0[i] = *(const bf16x8*)(a0p + i * 32);
    pa1[i] = *(const bf16x8*)(a1p + i * 32);
  }
  bf16x8 bqA[8], bqB[8];
  PFPAIR(bqA, 0)
#pragma unroll 1
  for (int kb = 0; kb < 32; kb += 8) {
    PFPAIR(bqB, kb + 2)
    MFMAPAIR(bqA, 0)
    PFPAIR(bqA, kb + 4)
    MFMAPAIR(bqB, 2)
    PFPAIR(bqB, kb + 6)
    MFMAPAIR(bqA, 4)
    PFPAIR(bqA, kb + 8)   // next iteration's first pair (wraps harmlessly at end)
    MFMAPAIR(bqB, 6)
  }
}

#undef PFPAIR
#undef MFMAPAIR

// ---- slow/fallback barrier (agent scope, R9-validated form) ----
__device__ __forceinline__ void group_barrier(unsigned* ctr, unsigned target) {
  __syncthreads();  // all waves' stores issued & drained to L2
  if (threadIdx.x == 0) {
    __hip_atomic_fetch_add(ctr, 1u, __ATOMIC_RELEASE, __HIP_MEMORY_SCOPE_AGENT);
    while (__hip_atomic_load(ctr, __ATOMIC_RELAXED, __HIP_MEMORY_SCOPE_AGENT) < target)
      __builtin_amdgcn_s_sleep(2);
    (void)__hip_atomic_load(ctr, __ATOMIC_ACQUIRE, __HIP_MEMORY_SCOPE_AGENT);
  }
  __syncthreads();
}

// ---- fast barrier (group verified XCD-homogeneous): h stays in XCD L2 ----
// (R10-validated: WRITE_SIZE 246 MB -> 22 MB.) Relaxed MALL signal/poll, one
// L1-only invalidate (buffer_inv sc0) on the consumer.
__device__ __forceinline__ void group_barrier_l2(unsigned* ctr, unsigned target) {
  __syncthreads();  // h stores of all 8 waves now visible in XCD L2
  if (threadIdx.x == 0) {
    __hip_atomic_fetch_add(ctr, 1u, __ATOMIC_RELAXED, __HIP_MEMORY_SCOPE_AGENT);
    while (__hip_atomic_load(ctr, __ATOMIC_RELAXED, __HIP_MEMORY_SCOPE_AGENT) < target)
      __builtin_amdgcn_s_sleep(2);
    asm volatile("buffer_inv sc0" ::: "memory");  // invalidate this CU's L1 only
  }
  __syncthreads();
}

// 256 blocks x 512 threads, 1 block/CU (LDS-bound). Block (mt,nt):
// M rows [mt*256,+256), N cols [nt*64,+64). Group = blocks sharing mt
// (bid&15) — closed under the h dependency, swizzled onto one XCD.
// Barrier slot layout (128 B): [0]=step ctr, [1]=publish, [2]=XCD mask.
__global__ __launch_bounds__(512, 1) void rnn_coop(
    const unsigned short* __restrict__ x_bf,  // [4096][1024] bf16
    const unsigned short* __restrict__ Wi,    // [1024][1024] bf16 (scaled)
    const unsigned short* __restrict__ Wr,    // [1024][1024] bf16 (scaled)
    const float* __restrict__ b_in,
    const float* __restrict__ b_rec,
    unsigned short* __restrict__ hA,
    unsigned short* __restrict__ hB,
    unsigned* __restrict__ bar,
    Mods mods) {
  __shared__ __align__(16) unsigned short ws[64 * 1032];
  __shared__ unsigned fastflag;

  const int tid = threadIdx.x;
  const int w = tid >> 6, lane = tid & 63;
  const int lrow = lane & 15, quad = lane >> 4;
  const int bid = (int)blockIdx.x;
  const int mt = (bid & 7) * 2 + ((bid >> 3) & 1);
  const int nt = bid >> 4;
  const int gid = bid & 15;
  const int m0 = mt * 256 + w * 32;
  const int n0 = nt * 64;
  unsigned* ctr = bar + gid * 32;  // 128 B per group

  // ---- publish this block's physical XCD at entry (R10 protocol) ----
  if (tid == 0) {
    unsigned xcc;
    asm volatile("s_getreg_b32 %0, hwreg(HW_REG_XCC_ID)" : "=s"(xcc));
    __hip_atomic_fetch_or(ctr + 2, 1u << (xcc & 15u), __ATOMIC_RELAXED,
                          __HIP_MEMORY_SCOPE_AGENT);
    __hip_atomic_fetch_add(ctr + 1, 1u, __ATOMIC_RELEASE, __HIP_MEMORY_SCOPE_AGENT);
  }

  // per-lane biases: n = n0 + nf*16 + quad*4 + r  (swapped D-layout)
  float4 bin4[4], brec4[4];
#pragma unroll
  for (int nf = 0; nf < 4; ++nf) {
    bin4[nf] = *(const float4*)&b_in[n0 + nf * 16 + quad * 4];
    brec4[nf] = *(const float4*)&b_rec[n0 + nf * 16 + quad * 4];
  }

  // ---- phase A: xproj slice (registers) via Wi slice in ws ----
  load_ws(Wi + (size_t)n0 * 1024, ws, tid);
  __syncthreads();
  float xpr[2][4][4];  // [mf][nf][r]: m = m0+mf*16+lrow, n = n0+nf*16+quad*4+r
  {
    f32x4 xacc[2][4] = {};
    ksweep(&x_bf[(size_t)(m0 + lrow) * 1024 + quad * 8],
           &x_bf[(size_t)(m0 + 16 + lrow) * 1024 + quad * 8], ws, lrow, quad, xacc);
#pragma unroll
    for (int mf = 0; mf < 2; ++mf)
#pragma unroll
      for (int nf = 0; nf < 4; ++nf)
#pragma unroll
        for (int r = 0; r < 4; ++r)
          xpr[mf][nf][r] = xacc[mf][nf][r] + ((const float*)&bin4[nf])[r];
  }
  __syncthreads();  // all ws (Wi) reads done

  // ---- Wr slice -> ws (resident for all steps) ----
  load_ws(Wr + (size_t)n0 * 1024, ws, tid);

  // ---- resolve group homogeneity (relaxed MALL reads only; no acquire) ----
  if (tid == 0) {
    while (__hip_atomic_load(ctr + 1, __ATOMIC_RELAXED, __HIP_MEMORY_SCOPE_AGENT) < 16u)
      __builtin_amdgcn_s_sleep(2);
    asm volatile("" ::: "memory");  // keep mask read after the spin
    unsigned m = __hip_atomic_load(ctr + 2, __ATOMIC_RELAXED, __HIP_MEMORY_SCOPE_AGENT);
    fastflag = ((m & (m - 1u)) == 0u) ? 1u : 0u;
  }

  // ---- t=0: h = tanh(xproj + b_rec), mod(0)=1, h_prev=0 ----
  unsigned short* cur = hA;
  unsigned short* nxt = hB;
#pragma unroll
  for (int mf = 0; mf < 2; ++mf)
#pragma unroll
    for (int nf = 0; nf < 4; ++nf) {
      float h0 = tanh_fast(xpr[mf][nf][0] + ((const float*)&brec4[nf])[0]);
      float h1 = tanh_fast(xpr[mf][nf][1] + ((const float*)&brec4[nf])[1]);
      float h2 = tanh_fast(xpr[mf][nf][2] + ((const float*)&brec4[nf])[2]);
      float h3 = tanh_fast(xpr[mf][nf][3] + ((const float*)&brec4[nf])[3]);
      uint2 pk = {cvt_pk_bf16(h0, h1), cvt_pk_bf16(h2, h3)};
      *(uint2*)&cur[(size_t)(m0 + mf * 16 + lrow) * 1024 + n0 + nf * 16 + quad * 4] = pk;
    }
  __syncthreads();  // ws (Wr) ready + fastflag published
  const bool fastp = (fastflag != 0u);

  // ---- steps t = 1..29 ----
#pragma unroll 1
  for (int t = 1; t < 30; ++t) {
    if (fastp) group_barrier_l2(ctr, 16u * (unsigned)t);  // h(t-1) via XCD L2
    else       group_barrier(ctr, 16u * (unsigned)t);     // device-scope fallback
    const float mod = mods.m[t];
    f32x4 acc[2][4] = {};
    ksweep(&cur[(size_t)(m0 + lrow) * 1024 + quad * 8],
           &cur[(size_t)(m0 + 16 + lrow) * 1024 + quad * 8], ws, lrow, quad, acc);
#pragma unroll
    for (int mf = 0; mf < 2; ++mf)
#pragma unroll
      for (int nf = 0; nf < 4; ++nf) {
        float h0 = tanh_fast(xpr[mf][nf][0] +
                             (acc[mf][nf][0] + ((const float*)&brec4[nf])[0]) * mod);
        float h1 = tanh_fast(xpr[mf][nf][1] +
                             (acc[mf][nf][1] + ((const float*)&brec4[nf])[1]) * mod);
        float h2 = tanh_fast(xpr[mf][nf][2] +
                             (acc[mf][nf][2] + ((const float*)&brec4[nf])[2]) * mod);
        float h3 = tanh_fast(xpr[mf][nf][3] +
                             (acc[mf][nf][3] + ((const float*)&brec4[nf])[3]) * mod);
        uint2 pk = {cvt_pk_bf16(h0, h1), cvt_pk_bf16(h2, h3)};
        *(uint2*)&nxt[(size_t)(m0 + mf * 16 + lrow) * 1024 + n0 + nf * 16 + quad * 4] = pk;
      }
    unsigned short* tmp = cur; cur = nxt; nxt = tmp;
  }
  // h29 ends in hB (odd number of steps after t=0); kernel-end dispatch
  // release fence writes back dirty L2 for gemm_bt0.
}

extern "C" void kernel_launch(void* const* d_in, const int* in_sizes, int n_in,
                              void* d_out, int out_size, void* d_ws, size_t ws_size,
                              hipStream_t stream) {
  const float* x     = (const float*)d_in[0];
  const float* W_in  = (const float*)d_in[1];
  const float* b_in  = (const float*)d_in[2];
  const float* W_rec = (const float*)d_in[3];
  const float* b_rec = (const float*)d_in[4];
  const float* W_out = (const float*)d_in[5];
  const float* b_out = (const float*)d_in[6];
  const float* u_in  = (const float*)d_in[7];
  const float* u_rec = (const float*)d_in[8];
  const float* u_out = (const float*)d_in[9];

  const int B = 4096, H = 1024, DOUT = 256;

  char* w = (char*)d_ws;
  float* S = (float*)w;                          // 256 floats
  float* v = S + 256;                            // 3 x 1024 floats
  unsigned* bar = (unsigned*)(w + 14336);        // 16 groups x 128 B
  unsigned short* Wi_bf = (unsigned short*)(w + (1 << 14));
  unsigned short* Wr_bf = Wi_bf + (size_t)H * H;
  unsigned short* Wo_bf = Wr_bf + (size_t)H * H;
  unsigned short* x_bf  = Wo_bf + (size_t)DOUT * H;
  unsigned short* hA = x_bf + (size_t)B * H;
  unsigned short* hB = hA + (size_t)B * H;

  hipMemsetAsync(w, 0, 1 << 14, stream);  // zero S, v, barrier counters+masks

  dim3 t256(256);
  spec_col3<<<dim3(4, 16, 3), t256, 0, stream>>>(W_in, W_rec, W_out, u_in, u_rec, u_out, v);
  norm3<<<3, t256, 0, stream>>>(v, S);
  rowsq3<<<2304, t256, 0, stream>>>(W_in, W_rec, W_out, v, S);
  spec_finalize<<<1, 64, 0, stream>>>(S);
  cvt_all<<<1024, t256, 0, stream>>>((const float4*)W_in, (const float4*)W_rec,
                                     (const float4*)W_out, (const float4*)x, S,
                                     (ushort4*)Wi_bf, (ushort4*)Wr_bf,
                                     (ushort4*)Wo_bf, (ushort4*)x_bf);

  Mods mods;
  for (int t = 0; t < 32; ++t) mods.m[t] = (float)(1.0 + 0.1 * sin(0.3 * (double)t));
  {
    void* args[] = {(void*)&x_bf, (void*)&Wi_bf, (void*)&Wr_bf, (void*)&b_in,
                    (void*)&b_rec, (void*)&hA, (void*)&hB, (void*)&bar, (void*)&mods};
    hipLaunchCooperativeKernel((const void*)rnn_coop, dim3(256), dim3(512),
                               args, 0, stream);
  }

  // out = h29 @ Wo_n^T + b_out
  gemm_bt0<<<dim3(B / 64, DOUT / 128), t256, 0, stream>>>(
      hB, Wo_bf, b_out, (float*)d_out, B, DOUT, H);
}

// Round 7
// 778.515 us; speedup vs baseline: 1.5755x; 1.0032x over previous
//
#include <hip/hip_runtime.h>
#include <hip/hip_bf16.h>
#include <math.h>
#include <stdint.h>

// HolomorphicEqProp: B=4096, D_IN=H=1024, D_OUT=256, steps=30.
// Round-16: kill the LDS bank conflicts (single change on the R15 base).
//  Evidence: SQ_LDS_BANK_CONFLICT 3.34e7/dispatch = ~4300 extra cyc/CU/step
//  on a ~12300-cyc LDS floor; R14's lane-consecutive read shape measured 0
//  conflicts with the SAME row stride -> conflicts come from the 16-row x
//  4-quad b-frag read geometry, not padding.
//  Fix: MFMA-native tiled LDS layout ws[nf][kc][lane][8] — each (nf,kc)
//  16x32 subtile contiguous (1 KB), lane l reads bytes l*16..+15 (canonical
//  conflict-free pattern, m134). load_ws scatters accordingly (runs twice,
//  one-time). Sweep reads: per-lane base ws+lane*8 + compile-time
//  (nf*32+kc)*512 offsets. LDS 132->128 KB, still 1 block/CU.
//  Everything else EXACTLY the R15/649us kernel: 512 thr, 16x16x32 swapped
//  operands, paired LDS-frag double-buffer (bqA/bqB), global h ring-8,
//  cvt_pk epilogue, tanh_fast, R10 XCD-L2 lockstep barrier + fallback,
//  setprio around MFMA clusters.

#define EPSF 1e-12f

typedef short bf16x8 __attribute__((ext_vector_type(8)));
typedef float f32x4 __attribute__((ext_vector_type(4)));

struct Mods { float m[32]; };

__device__ __forceinline__ unsigned short f2bf(float f) {
  union { float f; unsigned u; } v; v.f = f;
  unsigned r = v.u + 0x7FFFu + ((v.u >> 16) & 1u);  // RNE
  return (unsigned short)(r >> 16);
}

// packed f32x2 -> bf16x2 (RNE), single VALU op
__device__ __forceinline__ unsigned cvt_pk_bf16(float lo, float hi) {
  unsigned r;
  asm("v_cvt_pk_bf16_f32 %0, %1, %2" : "=v"(r) : "v"(lo), "v"(hi));
  return r;
}

// tanh(x) = 1 - 2/(exp(2x)+1). Saturates exactly; abs err ~1e-7 << bf16 eps.
__device__ __forceinline__ float tanh_fast(float x) {
  float e = __expf(2.0f * x);
  float r = __builtin_amdgcn_rcpf(e + 1.0f);
  return fmaf(-2.0f, r, 1.0f);
}

// async global->LDS (only in gemm_bt0: R1-validated pattern)
__device__ __forceinline__ void async16(const void* g, void* l) {
  __builtin_amdgcn_global_load_lds(
      (__attribute__((address_space(1))) void*)(uintptr_t)(g),
      (__attribute__((address_space(3))) void*)(unsigned)(uintptr_t)(l),
      16, 0, 0);
}

__device__ __forceinline__ float block_reduce_sum(float x) {
#pragma unroll
  for (int o = 32; o > 0; o >>= 1) x += __shfl_down(x, o, 64);
  __shared__ float sm[8];
  int lane = threadIdx.x & 63, w = threadIdx.x >> 6;
  if (lane == 0) sm[w] = x;
  __syncthreads();
  float t = 0.f;
  if (threadIdx.x == 0) {
    int nw = (int)(blockDim.x >> 6);
    for (int i = 0; i < nw; ++i) t += sm[i];
  }
  return t;
}

// ---------------- fused spectral-norm setup (fp32, exact) ----------------

__global__ void spec_col3(const float* __restrict__ Wi, const float* __restrict__ Wr,
                          const float* __restrict__ Wo, const float* __restrict__ ui,
                          const float* __restrict__ ur, const float* __restrict__ uo,
                          float* __restrict__ v) {
  int z = blockIdx.z;
  const float* W = (z == 0) ? Wi : (z == 1) ? Wr : Wo;
  const float* u = (z == 0) ? ui : (z == 1) ? ur : uo;
  int M = (z == 2) ? 256 : 1024;
  int i0 = blockIdx.y * 64;
  if (i0 >= M) return;
  int j = blockIdx.x * blockDim.x + threadIdx.x;
  float acc = 0.f;
  for (int i = i0; i < i0 + 64; ++i)
    acc += W[(size_t)i * 1024 + j] * u[i];
  atomicAdd(&v[z * 1024 + j], acc);
}

__global__ void norm3(const float* __restrict__ v, float* __restrict__ S) {
  int z = blockIdx.x;
  float acc = 0.f;
  for (int i = threadIdx.x; i < 1024; i += blockDim.x) {
    float x = v[z * 1024 + i];
    acc += x * x;
  }
  float t = block_reduce_sum(acc);
  if (threadIdx.x == 0) S[z] = t;
}

__global__ void rowsq3(const float* __restrict__ Wi, const float* __restrict__ Wr,
                       const float* __restrict__ Wo, const float* __restrict__ v,
                       float* __restrict__ S) {
  int bid = blockIdx.x;
  int z = (bid < 1024) ? 0 : (bid < 2048) ? 1 : 2;
  int row = bid - ((z == 0) ? 0 : (z == 1) ? 1024 : 2048);
  const float* W = (z == 0) ? Wi : (z == 1) ? Wr : Wo;
  const float* vv = v + z * 1024;
  float acc = 0.f;
  for (int j = threadIdx.x; j < 1024; j += blockDim.x)
    acc += W[(size_t)row * 1024 + j] * vv[j];
  float r = block_reduce_sum(acc);
  if (threadIdx.x == 0) atomicAdd(&S[3 + z], r * r);
}

__global__ void spec_finalize(float* S) {
  int m = threadIdx.x;
  if (m < 3) {
    float nv = sqrtf(S[m]);
    float inv = 1.f / (nv + EPSF);
    float u2sq = S[3 + m] * inv * inv;
    float nu = sqrtf(u2sq);
    float sigma = u2sq / (nu + EPSF);
    S[6 + m] = 1.f / sigma;
  }
}

__device__ __forceinline__ ushort4 cvt4e(float4 w, float s) {
  ushort4 r;
  r.x = f2bf(w.x * s); r.y = f2bf(w.y * s); r.z = f2bf(w.z * s); r.w = f2bf(w.w * s);
  return r;
}

__global__ void cvt_all(const float4* __restrict__ Wi, const float4* __restrict__ Wr,
                        const float4* __restrict__ Wo, const float4* __restrict__ x,
                        const float* __restrict__ S,
                        ushort4* __restrict__ oWi, ushort4* __restrict__ oWr,
                        ushort4* __restrict__ oWo, ushort4* __restrict__ ox) {
  float s6 = S[6], s7 = S[7], s8 = S[8];
  int stride = gridDim.x * blockDim.x;
  int t0 = blockIdx.x * blockDim.x + threadIdx.x;
  for (int i = t0; i < 262144; i += stride) oWi[i] = cvt4e(Wi[i], s6);
  for (int i = t0; i < 262144; i += stride) oWr[i] = cvt4e(Wr[i], s7);
  for (int i = t0; i < 65536; i += stride) oWo[i] = cvt4e(Wo[i], s8);
  for (int i = t0; i < 1048576; i += stride) ox[i] = cvt4e(x[i], 1.0f);
}

// C = A[M,K] . B[N,K]^T + bias[n], fp32 out. 64x128 tile (validated R5/R7).
__global__ __launch_bounds__(256) void gemm_bt0(
    const unsigned short* __restrict__ A, const unsigned short* __restrict__ B,
    const float* __restrict__ bias, float* __restrict__ outF,
    int M, int N, int K) {
  constexpr int BM = 64, BN = 128, BK = 32;
  __shared__ __align__(16) unsigned short As[BM * BK];
  __shared__ __align__(16) unsigned short Bs[BN * BK];
  const int tid = threadIdx.x;
  const int wave = tid >> 6, lane = tid & 63;
  const int m0 = blockIdx.x * BM, n0 = blockIdx.y * BN;
  const int wm = (wave >> 1) * 32, wn = (wave & 1) * 64;
  const int lrow = lane & 15, quad = lane >> 4;

  f32x4 acc[2][4] = {};

  for (int k0 = 0; k0 < K; k0 += BK) {
    {
      int e = tid * 8;
      int r = e >> 5, c = e & 31;
      async16(&A[(size_t)(m0 + r) * K + k0 + c], &As[e]);
#pragma unroll
      for (int inst = 0; inst < 2; ++inst) {
        int eb = inst * 2048 + tid * 8;
        int rb = eb >> 5, cb = eb & 31;
        async16(&B[(size_t)(n0 + rb) * K + k0 + cb], &Bs[eb]);
      }
    }
    __syncthreads();

    bf16x8 af[2], bfr[4];
#pragma unroll
    for (int i = 0; i < 2; ++i)
      af[i] = *(const bf16x8*)&As[(wm + i * 16 + lrow) * BK + quad * 8];
#pragma unroll
    for (int j = 0; j < 4; ++j)
      bfr[j] = *(const bf16x8*)&Bs[(wn + j * 16 + lrow) * BK + quad * 8];
#pragma unroll
    for (int i = 0; i < 2; ++i)
#pragma unroll
      for (int j = 0; j < 4; ++j)
        acc[i][j] = __builtin_amdgcn_mfma_f32_16x16x32_bf16(af[i], bfr[j], acc[i][j], 0, 0, 0);
    __syncthreads();
  }

#pragma unroll
  for (int i = 0; i < 2; ++i)
#pragma unroll
    for (int j = 0; j < 4; ++j) {
      int col = n0 + wn + j * 16 + lrow;
      float bv = bias[col];
#pragma unroll
      for (int r = 0; r < 4; ++r) {
        int row = m0 + wm + i * 16 + quad * 4 + r;
        outF[(size_t)row * N + col] = acc[i][j][r] + bv;
      }
    }
}

// ---------------- cooperative RNN ----------------

// MFMA-native tiled LDS layout: ws[nf][kc][lane][8 shorts].
// Subtile (nf,kc) = rows nf*16..+15, cols kc*32..+31 of the 64x1024 slice,
// stored contiguously (1 KB) in the exact B-frag lane order
// (lane = lrow + 16*quad holds row lrow, cols quad*8..+7).
// Read: lane l touches bytes l*16..+15 of the subtile -> conflict-free.
__device__ __forceinline__ void load_ws(const unsigned short* __restrict__ src,
                                        unsigned short* ws, int tid) {
  int r = tid & 63, s = tid >> 6;     // source row r, col segment s (128 cols)
  int nf = r >> 4, lrow = r & 15;
  const unsigned short* p = src + (size_t)r * 1024 + s * 128;
#pragma unroll
  for (int j = 0; j < 16; ++j) {
    int c = s * 128 + j * 8;
    int kc = c >> 5, quad = (c >> 3) & 3;
    *(bf16x8*)&ws[((nf * 32 + kc) * 64 + (lrow + 16 * quad)) * 8] =
        *(const bf16x8*)(p + j * 8);
  }
}

// -------- K-sweep: paired LDS-frag double-buffer + global ring-8 --------
// wsl = ws + lane*8 (per-lane base); frag (nf,kc) at wsl + (nf*32+kc)*512.
// All buffer/ring indices compile-time (rule #20).

#define PFPAIR(DST, KP)                                                          \
  {                                                                              \
    const int kp_ = (KP) & 31;                                                   \
    _Pragma("unroll")                                                            \
    for (int nf = 0; nf < 4; ++nf) {                                             \
      DST[nf]     = *(const bf16x8*)(wsl + (nf * 32 + kp_) * 512);               \
      DST[nf + 4] = *(const bf16x8*)(wsl + (nf * 32 + kp_ + 1) * 512);           \
    }                                                                            \
  }

#define MFMAPAIR(BUF, OFF)                                                       \
  {                                                                              \
    const int kc0 = kb + (OFF), kc1 = kc0 + 1;                                   \
    bf16x8 a00 = pa0[(OFF) & 7], a10 = pa1[(OFF) & 7];                           \
    bf16x8 a01 = pa0[((OFF) + 1) & 7], a11 = pa1[((OFF) + 1) & 7];               \
    pa0[(OFF) & 7] = *(const bf16x8*)(a0p + ((kc0 + 8) & 31) * 32);              \
    pa1[(OFF) & 7] = *(const bf16x8*)(a1p + ((kc0 + 8) & 31) * 32);              \
    pa0[((OFF) + 1) & 7] = *(const bf16x8*)(a0p + ((kc1 + 8) & 31) * 32);        \
    pa1[((OFF) + 1) & 7] = *(const bf16x8*)(a1p + ((kc1 + 8) & 31) * 32);        \
    __builtin_amdgcn_s_setprio(1);                                               \
    acc[0][0] = __builtin_amdgcn_mfma_f32_16x16x32_bf16(BUF[0], a00, acc[0][0], 0, 0, 0); \
    acc[1][0] = __builtin_amdgcn_mfma_f32_16x16x32_bf16(BUF[0], a10, acc[1][0], 0, 0, 0); \
    acc[0][1] = __builtin_amdgcn_mfma_f32_16x16x32_bf16(BUF[1], a00, acc[0][1], 0, 0, 0); \
    acc[1][1] = __builtin_amdgcn_mfma_f32_16x16x32_bf16(BUF[1], a10, acc[1][1], 0, 0, 0); \
    acc[0][2] = __builtin_amdgcn_mfma_f32_16x16x32_bf16(BUF[2], a00, acc[0][2], 0, 0, 0); \
    acc[1][2] = __builtin_amdgcn_mfma_f32_16x16x32_bf16(BUF[2], a10, acc[1][2], 0, 0, 0); \
    acc[0][3] = __builtin_amdgcn_mfma_f32_16x16x32_bf16(BUF[3], a00, acc[0][3], 0, 0, 0); \
    acc[1][3] = __builtin_amdgcn_mfma_f32_16x16x32_bf16(BUF[3], a10, acc[1][3], 0, 0, 0); \
    acc[0][0] = __builtin_amdgcn_mfma_f32_16x16x32_bf16(BUF[4], a01, acc[0][0], 0, 0, 0); \
    acc[1][0] = __builtin_amdgcn_mfma_f32_16x16x32_bf16(BUF[4], a11, acc[1][0], 0, 0, 0); \
    acc[0][1] = __builtin_amdgcn_mfma_f32_16x16x32_bf16(BUF[5], a01, acc[0][1], 0, 0, 0); \
    acc[1][1] = __builtin_amdgcn_mfma_f32_16x16x32_bf16(BUF[5], a11, acc[1][1], 0, 0, 0); \
    acc[0][2] = __builtin_amdgcn_mfma_f32_16x16x32_bf16(BUF[6], a01, acc[0][2], 0, 0, 0); \
    acc[1][2] = __builtin_amdgcn_mfma_f32_16x16x32_bf16(BUF[6], a11, acc[1][2], 0, 0, 0); \
    acc[0][3] = __builtin_amdgcn_mfma_f32_16x16x32_bf16(BUF[7], a01, acc[0][3], 0, 0, 0); \
    acc[1][3] = __builtin_amdgcn_mfma_f32_16x16x32_bf16(BUF[7], a11, acc[1][3], 0, 0, 0); \
    __builtin_amdgcn_s_setprio(0);                                               \
  }

__device__ __forceinline__ void ksweep(const unsigned short* __restrict__ a0p,
                                       const unsigned short* __restrict__ a1p,
                                       const unsigned short* wsl,
                                       f32x4 acc[2][4]) {
  bf16x8 pa0[8], pa1[8];
#pragma unroll
  for (int i = 0; i < 8; ++i) {
    pa0[i] = *(const bf16x8*)(a0p + i * 32);
    pa1[i] = *(const bf16x8*)(a1p + i * 32);
  }
  bf16x8 bqA[8], bqB[8];
  PFPAIR(bqA, 0)
#pragma unroll 1
  for (int kb = 0; kb < 32; kb += 8) {
    PFPAIR(bqB, kb + 2)
    MFMAPAIR(bqA, 0)
    PFPAIR(bqA, kb + 4)
    MFMAPAIR(bqB, 2)
    PFPAIR(bqB, kb + 6)
    MFMAPAIR(bqA, 4)
    PFPAIR(bqA, kb + 8)   // next iteration's first pair (wraps harmlessly at end)
    MFMAPAIR(bqB, 6)
  }
}

#undef PFPAIR
#undef MFMAPAIR

// ---- slow/fallback barrier (agent scope, R9-validated form) ----
__device__ __forceinline__ void group_barrier(unsigned* ctr, unsigned target) {
  __syncthreads();  // all waves' stores issued & drained to L2
  if (threadIdx.x == 0) {
    __hip_atomic_fetch_add(ctr, 1u, __ATOMIC_RELEASE, __HIP_MEMORY_SCOPE_AGENT);
    while (__hip_atomic_load(ctr, __ATOMIC_RELAXED, __HIP_MEMORY_SCOPE_AGENT) < target)
      __builtin_amdgcn_s_sleep(2);
    (void)__hip_atomic_load(ctr, __ATOMIC_ACQUIRE, __HIP_MEMORY_SCOPE_AGENT);
  }
  __syncthreads();
}

// ---- fast barrier (group verified XCD-homogeneous): h stays in XCD L2 ----
// (R10-validated: WRITE_SIZE 246 MB -> 22 MB.) Relaxed MALL signal/poll, one
// L1-only invalidate (buffer_inv sc0) on the consumer.
__device__ __forceinline__ void group_barrier_l2(unsigned* ctr, unsigned target) {
  __syncthreads();  // h stores of all 8 waves now visible in XCD L2
  if (threadIdx.x == 0) {
    __hip_atomic_fetch_add(ctr, 1u, __ATOMIC_RELAXED, __HIP_MEMORY_SCOPE_AGENT);
    while (__hip_atomic_load(ctr, __ATOMIC_RELAXED, __HIP_MEMORY_SCOPE_AGENT) < target)
      __builtin_amdgcn_s_sleep(2);
    asm volatile("buffer_inv sc0" ::: "memory");  // invalidate this CU's L1 only
  }
  __syncthreads();
}

// 256 blocks x 512 threads, 1 block/CU (LDS-bound). Block (mt,nt):
// M rows [mt*256,+256), N cols [nt*64,+64). Group = blocks sharing mt
// (bid&15) — closed under the h dependency, swizzled onto one XCD.
// Barrier slot layout (128 B): [0]=step ctr, [1]=publish, [2]=XCD mask.
__global__ __launch_bounds__(512, 1) void rnn_coop(
    const unsigned short* __restrict__ x_bf,  // [4096][1024] bf16
    const unsigned short* __restrict__ Wi,    // [1024][1024] bf16 (scaled)
    const unsigned short* __restrict__ Wr,    // [1024][1024] bf16 (scaled)
    const float* __restrict__ b_in,
    const float* __restrict__ b_rec,
    unsigned short* __restrict__ hA,
    unsigned short* __restrict__ hB,
    unsigned* __restrict__ bar,
    Mods mods) {
  __shared__ __align__(16) unsigned short ws[4 * 32 * 512];  // 128 KB tiled
  __shared__ unsigned fastflag;

  const int tid = threadIdx.x;
  const int w = tid >> 6, lane = tid & 63;
  const int lrow = lane & 15, quad = lane >> 4;
  const int bid = (int)blockIdx.x;
  const int mt = (bid & 7) * 2 + ((bid >> 3) & 1);
  const int nt = bid >> 4;
  const int gid = bid & 15;
  const int m0 = mt * 256 + w * 32;
  const int n0 = nt * 64;
  unsigned* ctr = bar + gid * 32;  // 128 B per group
  const unsigned short* wsl = ws + lane * 8;  // per-lane tiled base

  // ---- publish this block's physical XCD at entry (R10 protocol) ----
  if (tid == 0) {
    unsigned xcc;
    asm volatile("s_getreg_b32 %0, hwreg(HW_REG_XCC_ID)" : "=s"(xcc));
    __hip_atomic_fetch_or(ctr + 2, 1u << (xcc & 15u), __ATOMIC_RELAXED,
                          __HIP_MEMORY_SCOPE_AGENT);
    __hip_atomic_fetch_add(ctr + 1, 1u, __ATOMIC_RELEASE, __HIP_MEMORY_SCOPE_AGENT);
  }

  // per-lane biases: n = n0 + nf*16 + quad*4 + r  (swapped D-layout)
  float4 bin4[4], brec4[4];
#pragma unroll
  for (int nf = 0; nf < 4; ++nf) {
    bin4[nf] = *(const float4*)&b_in[n0 + nf * 16 + quad * 4];
    brec4[nf] = *(const float4*)&b_rec[n0 + nf * 16 + quad * 4];
  }

  // ---- phase A: xproj slice (registers) via Wi slice in ws ----
  load_ws(Wi + (size_t)n0 * 1024, ws, tid);
  __syncthreads();
  float xpr[2][4][4];  // [mf][nf][r]: m = m0+mf*16+lrow, n = n0+nf*16+quad*4+r
  {
    f32x4 xacc[2][4] = {};
    ksweep(&x_bf[(size_t)(m0 + lrow) * 1024 + quad * 8],
           &x_bf[(size_t)(m0 + 16 + lrow) * 1024 + quad * 8], wsl, xacc);
#pragma unroll
    for (int mf = 0; mf < 2; ++mf)
#pragma unroll
      for (int nf = 0; nf < 4; ++nf)
#pragma unroll
        for (int r = 0; r < 4; ++r)
          xpr[mf][nf][r] = xacc[mf][nf][r] + ((const float*)&bin4[nf])[r];
  }
  __syncthreads();  // all ws (Wi) reads done

  // ---- Wr slice -> ws (resident for all steps) ----
  load_ws(Wr + (size_t)n0 * 1024, ws, tid);

  // ---- resolve group homogeneity (relaxed MALL reads only; no acquire) ----
  if (tid == 0) {
    while (__hip_atomic_load(ctr + 1, __ATOMIC_RELAXED, __HIP_MEMORY_SCOPE_AGENT) < 16u)
      __builtin_amdgcn_s_sleep(2);
    asm volatile("" ::: "memory");  // keep mask read after the spin
    unsigned m = __hip_atomic_load(ctr + 2, __ATOMIC_RELAXED, __HIP_MEMORY_SCOPE_AGENT);
    fastflag = ((m & (m - 1u)) == 0u) ? 1u : 0u;
  }

  // ---- t=0: h = tanh(xproj + b_rec), mod(0)=1, h_prev=0 ----
  unsigned short* cur = hA;
  unsigned short* nxt = hB;
#pragma unroll
  for (int mf = 0; mf < 2; ++mf)
#pragma unroll
    for (int nf = 0; nf < 4; ++nf) {
      float h0 = tanh_fast(xpr[mf][nf][0] + ((const float*)&brec4[nf])[0]);
      float h1 = tanh_fast(xpr[mf][nf][1] + ((const float*)&brec4[nf])[1]);
      float h2 = tanh_fast(xpr[mf][nf][2] + ((const float*)&brec4[nf])[2]);
      float h3 = tanh_fast(xpr[mf][nf][3] + ((const float*)&brec4[nf])[3]);
      uint2 pk = {cvt_pk_bf16(h0, h1), cvt_pk_bf16(h2, h3)};
      *(uint2*)&cur[(size_t)(m0 + mf * 16 + lrow) * 1024 + n0 + nf * 16 + quad * 4] = pk;
    }
  __syncthreads();  // ws (Wr) ready + fastflag published
  const bool fastp = (fastflag != 0u);

  // ---- steps t = 1..29 ----
#pragma unroll 1
  for (int t = 1; t < 30; ++t) {
    if (fastp) group_barrier_l2(ctr, 16u * (unsigned)t);  // h(t-1) via XCD L2
    else       group_barrier(ctr, 16u * (unsigned)t);     // device-scope fallback
    const float mod = mods.m[t];
    f32x4 acc[2][4] = {};
    ksweep(&cur[(size_t)(m0 + lrow) * 1024 + quad * 8],
           &cur[(size_t)(m0 + 16 + lrow) * 1024 + quad * 8], wsl, acc);
#pragma unroll
    for (int mf = 0; mf < 2; ++mf)
#pragma unroll
      for (int nf = 0; nf < 4; ++nf) {
        float h0 = tanh_fast(xpr[mf][nf][0] +
                             (acc[mf][nf][0] + ((const float*)&brec4[nf])[0]) * mod);
        float h1 = tanh_fast(xpr[mf][nf][1] +
                             (acc[mf][nf][1] + ((const float*)&brec4[nf])[1]) * mod);
        float h2 = tanh_fast(xpr[mf][nf][2] +
                             (acc[mf][nf][2] + ((const float*)&brec4[nf])[2]) * mod);
        float h3 = tanh_fast(xpr[mf][nf][3] +
                             (acc[mf][nf][3] + ((const float*)&brec4[nf])[3]) * mod);
        uint2 pk = {cvt_pk_bf16(h0, h1), cvt_pk_bf16(h2, h3)};
        *(uint2*)&nxt[(size_t)(m0 + mf * 16 + lrow) * 1024 + n0 + nf * 16 + quad * 4] = pk;
      }
    unsigned short* tmp = cur; cur = nxt; nxt = tmp;
  }
  // h29 ends in hB (odd number of steps after t=0); kernel-end dispatch
  // release fence writes back dirty L2 for gemm_bt0.
}

extern "C" void kernel_launch(void* const* d_in, const int* in_sizes, int n_in,
                              void* d_out, int out_size, void* d_ws, size_t ws_size,
                              hipStream_t stream) {
  const float* x     = (const float*)d_in[0];
  const float* W_in  = (const float*)d_in[1];
  const float* b_in  = (const float*)d_in[2];
  const float* W_rec = (const float*)d_in[3];
  const float* b_rec = (const float*)d_in[4];
  const float* W_out = (const float*)d_in[5];
  const float* b_out = (const float*)d_in[6];
  const float* u_in  = (const float*)d_in[7];
  const float* u_rec = (const float*)d_in[8];
  const float* u_out = (const float*)d_in[9];

  const int B = 4096, H = 1024, DOUT = 256;

  char* w = (char*)d_ws;
  float* S = (float*)w;                          // 256 floats
  float* v = S + 256;                            // 3 x 1024 floats
  unsigned* bar = (unsigned*)(w + 14336);        // 16 groups x 128 B
  unsigned short* Wi_bf = (unsigned short*)(w + (1 << 14));
  unsigned short* Wr_bf = Wi_bf + (size_t)H * H;
  unsigned short* Wo_bf = Wr_bf + (size_t)H * H;
  unsigned short* x_bf  = Wo_bf + (size_t)DOUT * H;
  unsigned short* hA = x_bf + (size_t)B * H;
  unsigned short* hB = hA + (size_t)B * H;

  hipMemsetAsync(w, 0, 1 << 14, stream);  // zero S, v, barrier counters+masks

  dim3 t256(256);
  spec_col3<<<dim3(4, 16, 3), t256, 0, stream>>>(W_in, W_rec, W_out, u_in, u_rec, u_out, v);
  norm3<<<3, t256, 0, stream>>>(v, S);
  rowsq3<<<2304, t256, 0, stream>>>(W_in, W_rec, W_out, v, S);
  spec_finalize<<<1, 64, 0, stream>>>(S);
  cvt_all<<<1024, t256, 0, stream>>>((const float4*)W_in, (const float4*)W_rec,
                                     (const float4*)W_out, (const float4*)x, S,
                                     (ushort4*)Wi_bf, (ushort4*)Wr_bf,
                                     (ushort4*)Wo_bf, (ushort4*)x_bf);

  Mods mods;
  for (int t = 0; t < 32; ++t) mods.m[t] = (float)(1.0 + 0.1 * sin(0.3 * (double)t));
  {
    void* args[] = {(void*)&x_bf, (void*)&Wi_bf, (void*)&Wr_bf, (void*)&b_in,
                    (void*)&b_rec, (void*)&hA, (void*)&hB, (void*)&bar, (void*)&mods};
    hipLaunchCooperativeKernel((const void*)rnn_coop, dim3(256), dim3(512),
                               args, 0, stream);
  }

  // out = h29 @ Wo_n^T + b_out
  gemm_bt0<<<dim3(B / 64, DOUT / 128), t256, 0, stream>>>(
      hB, Wo_bf, b_out, (float*)d_out, B, DOUT, H);
}